// Round 18
// baseline (374.769 us; speedup 1.0000x reference)
//
#include <hip/hip_runtime.h>
#include <math.h>

#define BATCH 8
#define CH    192
#define WW    56
#define NPTS  3136
#define C2    384
#define CG    96
#define MT    32
#define MSPLIT 4
#define LK    12
#define NCAND (MSPLIT*LK)
#define NREF  16
#define MQ    (NPTS/MSPLIT)   // 784 rows per m-quarter; 784 = 24*32 + 16
#define NT128 25              // ceil(3136/128)

typedef float f32x4 __attribute__((ext_vector_type(4)));
typedef short bf16x8 __attribute__((ext_vector_type(8)));

__device__ __forceinline__ float gelu_exact(float v) {
  return 0.5f * v * (1.0f + erff(v * 0.7071067811865475f));
}
__device__ __forceinline__ unsigned short f2bf(float f) {
  unsigned int u = __float_as_uint(f);
  u = u + 0x7fffu + ((u >> 16) & 1u);
  return (unsigned short)(u >> 16);
}
__device__ __forceinline__ float bf2f(unsigned short h) {
  return __uint_as_float(((unsigned int)h) << 16);
}
__device__ __forceinline__ void gl_lds16(const void* g, void* lds) {
  __builtin_amdgcn_global_load_lds(
      (const __attribute__((address_space(1))) unsigned int*)g,
      (__attribute__((address_space(3))) unsigned int*)lds, 16, 0, 0);
}
// order-preserving f32 -> u32 (ascending)
__device__ __forceinline__ unsigned fmono(float f) {
  unsigned u = __float_as_uint(f);
  return u ^ ((unsigned)((int)u >> 31) | 0x80000000u);
}
__device__ __forceinline__ unsigned umin32(unsigned a, unsigned b) { return a < b ? a : b; }
__device__ __forceinline__ unsigned umax32(unsigned a, unsigned b) { return a < b ? b : a; }

// pruned-bitonic merge of sorted-12 list with 4 new keys; comparator network
// verbatim from the r13-verified version -> identical output set/order.
__device__ __forceinline__ void merge12(unsigned (&ld)[LK], const unsigned* kk) {
  unsigned sa = umax32(kk[0], kk[1]), sb = umin32(kk[0], kk[1]);
  unsigned sc = umax32(kk[2], kk[3]), sd = umin32(kk[2], kk[3]);
  unsigned v0 = umax32(sa, sc), t1 = umin32(sa, sc);
  unsigned t2 = umax32(sb, sd), v3 = umin32(sb, sd);
  unsigned v1 = umax32(t1, t2), v2 = umin32(t1, t2);
  unsigned l4 = umin32(ld[4], v0), g4 = umax32(ld[4], v0);
  unsigned l5 = umin32(ld[5], v1), g5 = umax32(ld[5], v1);
  unsigned l6 = umin32(ld[6], v2), g6 = umax32(ld[6], v2);
  unsigned l7 = umin32(ld[7], v3), g7 = umax32(ld[7], v3);
  unsigned a0 = umin32(ld[0], l4), b0 = umax32(ld[0], l4);
  unsigned a1 = umin32(ld[1], l5), b1 = umax32(ld[1], l5);
  unsigned a2 = umin32(ld[2], l6), b2 = umax32(ld[2], l6);
  unsigned a3 = umin32(ld[3], l7), b3 = umax32(ld[3], l7);
  unsigned q0 = umin32(a0, a2), q2 = umax32(a0, a2);
  unsigned q1 = umin32(a1, a3), q3 = umax32(a1, a3);
  unsigned r0 = umin32(b0, b2), r2 = umax32(b0, b2);
  unsigned r1 = umin32(b1, b3), r3 = umax32(b1, b3);
  ld[0] = umin32(q0, q1); ld[1] = umax32(q0, q1);
  ld[2] = umin32(q2, q3); ld[3] = umax32(q2, q3);
  ld[4] = umin32(r0, r1); ld[5] = umax32(r0, r1);
  ld[6] = umin32(r2, r3); ld[7] = umax32(r2, r3);
  unsigned e0 = umin32(ld[8],  g4);
  unsigned e1 = umin32(ld[9],  g5);
  unsigned e2 = umin32(ld[10], g6);
  unsigned e3 = umin32(ld[11], g7);
  unsigned f0 = umin32(e0, e2), f2 = umax32(e0, e2);
  unsigned f1 = umin32(e1, e3), f3 = umax32(e1, e3);
  ld[8]  = umin32(f0, f1); ld[9]  = umax32(f0, f1);
  ld[10] = umin32(f2, f3); ld[11] = umax32(f2, f3);
}

// ---------------- K0: fold BN into weights; wg & w2 -> bf16 hi/lo; cos-table ----------------
// fc1 weights stay f32: h feeds neighbor selection; only the bitwise-stable
// f32 recipe is flip-safe (round-10 lesson).
__global__ void prep_kernel(
    const float* __restrict__ fc1_w, const float* __restrict__ fc1_b,
    const float* __restrict__ bn1_g, const float* __restrict__ bn1_b,
    const float* __restrict__ bn1_m, const float* __restrict__ bn1_v,
    const float* __restrict__ gc_w,  const float* __restrict__ gc_b,
    const float* __restrict__ bng_g, const float* __restrict__ bng_b,
    const float* __restrict__ bng_m, const float* __restrict__ bng_v,
    const float* __restrict__ fc2_w, const float* __restrict__ fc2_b,
    const float* __restrict__ bn2_g, const float* __restrict__ bn2_b,
    const float* __restrict__ bn2_m, const float* __restrict__ bn2_v,
    float* __restrict__ w1, float* __restrict__ b1,
    unsigned short* __restrict__ wgh, unsigned short* __restrict__ wgl,
    float* __restrict__ bg,
    unsigned short* __restrict__ w2h, unsigned short* __restrict__ w2l,
    float* __restrict__ b2, float* __restrict__ ftab)
{
  int i = blockIdx.x * 256 + threadIdx.x;
  if (i < 36864) {
    int d = i / CH;
    float s = bn1_g[d] / sqrtf(bn1_v[d] + 1e-5f);
    w1[i] = fc1_w[i] * s;
  } else if (i < 37056) {
    int d = i - 36864;
    float s = bn1_g[d] / sqrtf(bn1_v[d] + 1e-5f);
    b1[d] = (fc1_b[d] - bn1_m[d]) * s + bn1_b[d];
  } else if (i < 73920) {
    int j = i - 37056;
    int o = j / CG;
    float s = bng_g[o] / sqrtf(bng_v[o] + 1e-5f);
    float v = gc_w[j] * s;
    unsigned short hi = f2bf(v);
    wgh[j] = hi;
    wgl[j] = f2bf(v - bf2f(hi));
  } else if (i < 74304) {
    int o = i - 73920;
    float s = bng_g[o] / sqrtf(bng_v[o] + 1e-5f);
    bg[o] = (gc_b[o] - bng_m[o]) * s + bng_b[o];
  } else if (i < 148032) {
    int j = i - 74304;
    int d = j / C2;
    float s = bn2_g[d] / sqrtf(bn2_v[d] + 1e-5f);
    float v = fc2_w[j] * s;
    unsigned short hi = f2bf(v);
    w2h[j] = hi;
    w2l[j] = f2bf(v - bf2f(hi));
  } else if (i < 148224) {
    int d = i - 148032;
    float s = bn2_g[d] / sqrtf(bn2_v[d] + 1e-5f);
    b2[d] = (fc2_b[d] - bn2_m[d]) * s + bn2_b[d];
  } else if (i < 148280) {
    int delta = i - 148224;
    float s = 0.f;
    for (int t = 0; t < 48; ++t) {
      float omega = powf(10000.f, -(float)t / 48.f);
      s += cosf((float)delta * omega);
    }
    ftab[delta] = s * (-2.0f / (float)CH);   // pre-scaled: rel = ft[dy]+ft[dx]
  }
}

// ---------------- K0b: exact transpose x -> xt[b][n][k] (bitwise copy) ----------------
__global__ __launch_bounds__(256) void xt_kernel(
    const float* __restrict__ x, float* __restrict__ xt)
{
  __shared__ float T[64 * 65];
  const int tid = threadIdx.x;
  const int nt = blockIdx.x, kt = blockIdx.y, b = blockIdx.z;
  const int n0 = nt * 64, k0 = kt * 64;
  const float* xb = x + (size_t)b * CH * NPTS;
#pragma unroll
  for (int p = 0; p < 16; ++p) {
    int e = p * 256 + tid;
    int kk = e >> 6, r = e & 63;
    T[kk * 65 + r] = xb[(size_t)(k0 + kk) * NPTS + n0 + r];
  }
  __syncthreads();
#pragma unroll
  for (int p = 0; p < 4; ++p) {
    int e = p * 256 + tid;
    int r = e >> 4, k4 = (e & 15) << 2;
    float4 v;
    v.x = T[(k4 + 0) * 65 + r];
    v.y = T[(k4 + 1) * 65 + r];
    v.z = T[(k4 + 2) * 65 + r];
    v.w = T[(k4 + 3) * 65 + r];
    *(float4*)&xt[((size_t)b * NPTS + n0 + r) * CH + k0 + k4] = v;
  }
}

// ---------------- K1: h = BN1(fc1) ; f32 64x64 tile, swizzled LDS (r17 form) ----------------
__global__ __launch_bounds__(256) void fc1_kernel(
    const float* __restrict__ xt, const float* __restrict__ w1,
    const float* __restrict__ b1, float* __restrict__ h)
{
  __shared__ float As[64*68];
  __shared__ float Bs[64*68];
  const int tid = threadIdx.x;
  const int ntile = blockIdx.x, dt = blockIdx.y, b = blockIdx.z;
  const int n0 = ntile * 64, d0 = dt * 64;
  const int ty = tid >> 4, tx = tid & 15;
  const float* xa = xt + ((size_t)b * NPTS + n0) * CH;
  const float* wb = w1 + (size_t)d0 * CH;
  const int tya = ty & 7, txa = tx & 7;
  float acc[4][4] = {};
  for (int k0 = 0; k0 < CH; k0 += 64) {
    if (k0) __syncthreads();
#pragma unroll
    for (int p = 0; p < 4; ++p) {
      int e = p * 256 + tid;
      int r = e >> 4, c4 = e & 15;
      int col = (c4 ^ ((r >> 2) & 7)) << 2;
      *(float4*)&As[r*68 + col] = *(const float4*)&xa[(size_t)r * CH + k0 + (c4 << 2)];
      *(float4*)&Bs[r*68 + col] = *(const float4*)&wb[(size_t)r * CH + k0 + (c4 << 2)];
    }
    __syncthreads();
#pragma unroll
    for (int kq = 0; kq < 16; ++kq) {
      const int ca = (kq ^ tya) << 2;
      const int cb = (kq ^ txa) << 2;
      float4 av[4], bv[4];
#pragma unroll
      for (int i = 0; i < 4; ++i) av[i] = *(const float4*)&As[(ty*4+i)*68 + ca];
#pragma unroll
      for (int j = 0; j < 4; ++j) bv[j] = *(const float4*)&Bs[(tx*4+j)*68 + cb];
#pragma unroll
      for (int i = 0; i < 4; ++i)
#pragma unroll
        for (int j = 0; j < 4; ++j)
          acc[i][j] += av[i].x*bv[j].x + av[i].y*bv[j].y + av[i].z*bv[j].z + av[i].w*bv[j].w;
    }
  }
#pragma unroll
  for (int i = 0; i < 4; ++i) {
    int n = n0 + ty*4 + i;
    float4 v;
    v.x = acc[i][0] + b1[d0 + tx*4 + 0];
    v.y = acc[i][1] + b1[d0 + tx*4 + 1];
    v.z = acc[i][2] + b1[d0 + tx*4 + 2];
    v.w = acc[i][3] + b1[d0 + tx*4 + 3];
    *(float4*)&h[((size_t)b * NPTS + n) * CH + d0 + tx*4] = v;
  }
}

// ---------------- K2: xn (f32 + bf16 hi/lo split) + sq ----------------
__global__ __launch_bounds__(256) void norm_kernel(
    const float* __restrict__ h, float* __restrict__ xnf,
    unsigned short* __restrict__ xhi, unsigned short* __restrict__ xlo,
    float* __restrict__ sqv)
{
  const int lane = threadIdx.x & 63;
  const int row = blockIdx.x * 4 + (threadIdx.x >> 6);
  const float* hr = h + (size_t)row * CH;
  float v0 = hr[lane], v1 = hr[lane + 64], v2 = hr[lane + 128];
  float s = v0*v0 + v1*v1 + v2*v2;
#pragma unroll
  for (int o = 32; o > 0; o >>= 1) s += __shfl_xor(s, o);
  float inv = 1.0f / fmaxf(sqrtf(s), 1e-12f);
  float x0 = v0 * inv, x1 = v1 * inv, x2 = v2 * inv;
  size_t base = (size_t)row * CH;
  xnf[base + lane      ] = x0;
  xnf[base + lane + 64 ] = x1;
  xnf[base + lane + 128] = x2;
  unsigned short h0 = f2bf(x0), h1 = f2bf(x1), h2 = f2bf(x2);
  xhi[base + lane      ] = h0;
  xhi[base + lane + 64 ] = h1;
  xhi[base + lane + 128] = h2;
  xlo[base + lane      ] = f2bf(x0 - bf2f(h0));
  xlo[base + lane + 64 ] = f2bf(x1 - bf2f(h1));
  xlo[base + lane + 128] = f2bf(x2 - bf2f(h2));
  if (lane == 0) sqv[row] = s * inv * inv;
}

// ---------------- K3: MFMA coarse dist, 128-n blocks, per-lane packed-key top-12 ----------------
// Each wave owns TWO 16-n register B-sets: per staged m-tile the same 24
// ds_read_b128 now feed 72 MFMAs (read/MFMA ratio halved) and grid drops to
// 800 blocks (chip-total barriers/staging halved). Per-(n,m) key math, batch
// grouping and merge sequence unchanged -> pd bitwise identical.
__global__ __launch_bounds__(256, 2) void topk_kernel(
    const unsigned short* __restrict__ xhi, const unsigned short* __restrict__ xlo,
    const float* __restrict__ fts_g,
    unsigned* __restrict__ pd)
{
  __shared__ __align__(16) char LDSbuf[2 * 24576];   // [buf][hi 12288 | lo 12288]
  __shared__ float ft[64];

  const int tid  = threadIdx.x;
  const int lane = tid & 63;
  const int w    = tid >> 6;
  const int bid  = blockIdx.x;
  const int b    = bid & 7;            // XCD-aligned (round-robin assumption)
  const int r_   = bid >> 3;
  const int ms   = r_ / NT128;
  const int nt   = r_ % NT128;
  const int n0 = nt * 128;
  const size_t rowbase = (size_t)b * NPTS;

  if (tid < 64) ft[tid] = (tid < 56) ? fts_g[tid] : 0.0f;

  const int ar = lane & 15;
  const int hi = lane >> 4;
  const int ak = hi * 8;

  // two B-sets (n-side) in registers; clamp invalid rows (discarded at tail)
  int nb0 = n0 + w * 16 + ar;       if (nb0 > NPTS - 1) nb0 = NPTS - 1;
  int nb1 = n0 + 64 + w * 16 + ar;  if (nb1 > NPTS - 1) nb1 = NPTS - 1;
  bf16x8 b0h[6], b0l[6], b1h[6], b1l[6];
  {
    const unsigned short* p0h = xhi + (rowbase + nb0) * CH + ak;
    const unsigned short* p0l = xlo + (rowbase + nb0) * CH + ak;
    const unsigned short* p1h = xhi + (rowbase + nb1) * CH + ak;
    const unsigned short* p1l = xlo + (rowbase + nb1) * CH + ak;
#pragma unroll
    for (int c = 0; c < 6; ++c) {
      b0h[c] = *(const bf16x8*)(p0h + c * 32);
      b0l[c] = *(const bf16x8*)(p0l + c * 32);
      b1h[c] = *(const bf16x8*)(p1h + c * 32);
      b1l[c] = *(const bf16x8*)(p1l + c * 32);
    }
  }
  const int yn0 = nb0 / WW, xq0 = nb0 % WW;
  const int yn1 = nb1 / WW, xq1 = nb1 % WW;

  unsigned ld0[LK], ld1[LK];
#pragma unroll
  for (int k = 0; k < LK; ++k) { ld0[k] = 0xFFFFFFFFu; ld1[k] = 0xFFFFFFFFu; }

  int srcb[6];
#pragma unroll
  for (int j = 0; j < 6; ++j) {
    int L = (w & 1) * 6144 + j * 1024 + lane * 16;
    int r = L / 384, off = L % 384;
    srcb[j] = r * 384 + (off ^ ((r & 7) << 4));
  }
  const int ldsb = (w >= 2 ? 12288 : 0) + (w & 1) * 6144;

  const int mbase = ms * MQ;
  const char* gb = (w < 2 ? (const char*)xhi : (const char*)xlo)
                   + (rowbase + mbase) * (CH * 2);

#define STAGE(BUF) do {                                                     \
  _Pragma("unroll")                                                         \
  for (int j = 0; j < 6; ++j)                                               \
    gl_lds16(gb + srcb[j], LDSbuf + (BUF) * 24576 + ldsb + j * 1024);       \
} while (0)

  STAGE(0);
  gb += 12288;

  int ym0 = ms * 14, xm0 = 0;

  for (int tt = 0; tt < 25; ++tt) {
    __syncthreads();                   // buf[tt&1] staged (vmcnt drained); prior reads done
    if (tt + 1 < 25) { STAGE((tt + 1) & 1); gb += 12288; }

    const int bufb = (tt & 1) * 24576;
    const int swz = (ar & 7) << 4;
    const float fdy00 = ft[abs(yn0 - ym0)];
    const float fdy01 = ft[abs(yn0 - ym0 - 1)];
    const float fdy10 = ft[abs(yn1 - ym0)];
    const float fdy11 = ft[abs(yn1 - ym0 - 1)];
    const int nrt = (tt == 24) ? 1 : 2;
#pragma unroll
    for (int rt = 0; rt < 2; ++rt) {
      if (rt >= nrt) break;
      const int rA = rt * 16 + ar;
      f32x4 a0hh = {}, a0hl = {}, a0lh = {};
      f32x4 a1hh = {}, a1hl = {}, a1lh = {};
#pragma unroll
      for (int c = 0; c < 6; ++c) {
        int off = bufb + rA * 384 + ((c * 64 + hi * 16) ^ swz);
        bf16x8 ah = *(const bf16x8*)(LDSbuf + off);
        bf16x8 al = *(const bf16x8*)(LDSbuf + off + 12288);
        a0hh = __builtin_amdgcn_mfma_f32_16x16x32_bf16(ah, b0h[c], a0hh, 0, 0, 0);
        a0hl = __builtin_amdgcn_mfma_f32_16x16x32_bf16(ah, b0l[c], a0hl, 0, 0, 0);
        a0lh = __builtin_amdgcn_mfma_f32_16x16x32_bf16(al, b0h[c], a0lh, 0, 0, 0);
        a1hh = __builtin_amdgcn_mfma_f32_16x16x32_bf16(ah, b1h[c], a1hh, 0, 0, 0);
        a1hl = __builtin_amdgcn_mfma_f32_16x16x32_bf16(ah, b1l[c], a1hl, 0, 0, 0);
        a1lh = __builtin_amdgcn_mfma_f32_16x16x32_bf16(al, b1h[c], a1lh, 0, 0, 0);
      }
      f32x4 s40, s41;
#pragma unroll
      for (int i = 0; i < 4; ++i) {
        s40[i] = a0hh[i] + (a0hl[i] + a0lh[i]);
        s41[i] = a1hh[i] + (a1hl[i] + a1lh[i]);
      }

      const int locb = tt * MT + rt * 16 + hi * 4;
      unsigned kk[4];
      // set 0
#pragma unroll
      for (int i = 0; i < 4; ++i) {
        int xm = xm0 + rt * 16 + hi * 4 + i;
        const bool wrap = (xm >= WW);
        if (wrap) xm -= WW;
        int dx = xq0 - xm; dx = dx < 0 ? -dx : dx;
        float d_ = (wrap ? fdy01 : fdy00) + ft[dx] - 2.0f * s40[i];
        kk[i] = (fmono(d_) & 0xFFFFFC00u) | (unsigned)(locb + i);
      }
      merge12(ld0, kk);
      // set 1
#pragma unroll
      for (int i = 0; i < 4; ++i) {
        int xm = xm0 + rt * 16 + hi * 4 + i;
        const bool wrap = (xm >= WW);
        if (wrap) xm -= WW;
        int dx = xq1 - xm; dx = dx < 0 ? -dx : dx;
        float d_ = (wrap ? fdy11 : fdy10) + ft[dx] - 2.0f * s41[i];
        kk[i] = (fmono(d_) & 0xFFFFFC00u) | (unsigned)(locb + i);
      }
      merge12(ld1, kk);
    }
    xm0 += MT;
    if (xm0 >= WW) { xm0 -= WW; ym0 += 1; }
  }

  // tail: 4-way merge per n across hi-lanes; 128 rows (2 sets), guarded writes
  __syncthreads();
  unsigned* Md = (unsigned*)LDSbuf;           // 256*24*4 = 24576 B
#pragma unroll
  for (int k = 0; k < LK; ++k) {
    Md[tid * 24 + k] = ld0[k];
    Md[tid * 24 + 12 + k] = ld1[k];
  }
  __syncthreads();
  if (tid < 128) {
    const int set = tid >> 6, t6 = tid & 63;
    const int wv = t6 >> 4, arr = t6 & 15;
    const int n = n0 + set * 64 + wv * 16 + arr;
    if (n < NPTS) {
      int lb[4];
#pragma unroll
      for (int hq = 0; hq < 4; ++hq) lb[hq] = (wv * 64 + hq * 16 + arr) * 24 + set * 12;
      int p0 = 0, p1 = 0, p2 = 0, p3 = 0;
      unsigned* od = pd + ((rowbase + n) * MSPLIT + ms) * LK;
      for (int k = 0; k < LK; ++k) {
        unsigned bk = Md[lb[0] + p0]; int bq = 0;
        unsigned v1 = Md[lb[1] + p1];
        if (v1 < bk) { bk = v1; bq = 1; }
        unsigned v2 = Md[lb[2] + p2];
        if (v2 < bk) { bk = v2; bq = 2; }
        unsigned v3 = Md[lb[3] + p3];
        if (v3 < bk) { bk = v3; bq = 3; }
        if (bq == 0) { if (p0 < LK-1) ++p0; else Md[lb[0]+p0] = 0xFFFFFFFFu; }
        else if (bq == 1) { if (p1 < LK-1) ++p1; else Md[lb[1]+p1] = 0xFFFFFFFFu; }
        else if (bq == 2) { if (p2 < LK-1) ++p2; else Md[lb[2]+p2] = 0xFFFFFFFFu; }
        else              { if (p3 < LK-1) ++p3; else Md[lb[3]+p3] = 0xFFFFFFFFu; }
        od[k] = bk;
      }
    }
  }
#undef STAGE
}

// ---------------- K3b: pool 48 packed coarse keys -> exact f32 refine -> top-9 ----------------
__global__ __launch_bounds__(256) void refine_kernel(
    const unsigned* __restrict__ pd,
    const float* __restrict__ xn, const float* __restrict__ sqv,
    const float* __restrict__ fts_g, int* __restrict__ nn)
{
  __shared__ unsigned allk[4][NCAND];
  __shared__ int      ci_s[4][NREF];
  __shared__ float ft[56];
  const int tid = threadIdx.x;
  const int w = tid >> 6, lane = tid & 63;
  if (tid < 56) ft[tid] = fts_g[tid];
  const int row = blockIdx.x * 4 + w;
  const int b = row / NPTS;
  const int n_loc = row - b * NPTS;

  if (lane < NCAND) allk[w][lane] = pd[(size_t)row * NCAND + lane];
  __syncthreads();
  if (lane < NCAND) {
    unsigned k0 = allk[w][lane];
    int rank = 0;
    for (int j = 0; j < NCAND; ++j) {
      unsigned kj = allk[w][j];
      rank += (kj < k0 || (kj == k0 && j < lane)) ? 1 : 0;
    }
    if (rank < NREF) ci_s[w][rank] = (lane / LK) * MQ + (int)(k0 & 1023u);
  }
  __syncthreads();

  const float* xrow = xn + (size_t)row * CH;
  float a0 = xrow[lane], a1 = xrow[lane + 64], a2 = xrow[lane + 128];
  const int yn_ = n_loc / WW, xq_ = n_loc % WW;
  const size_t xbase = (size_t)b * NPTS * CH;

  int cm[NREF];
  float xv0[NREF], xv1[NREF], xv2[NREF];
#pragma unroll
  for (int c = 0; c < NREF; ++c) {
    int m = ci_s[w][c];
    cm[c] = m;
    const float* xm = xn + xbase + (size_t)m * CH;
    xv0[c] = xm[lane];
    xv1[c] = xm[lane + 64];
    xv2[c] = xm[lane + 128];
  }

  float myd = INFINITY; int myi = 0x7fffffff;
#pragma unroll
  for (int c = 0; c < NREF; ++c) {
    float s = a0 * xv0[c] + a1 * xv1[c] + a2 * xv2[c];
#pragma unroll
    for (int o = 32; o > 0; o >>= 1) s += __shfl_xor(s, o);
    if (lane == c) {
      int m = cm[c];
      int ym = m / WW, xm_ = m % WW;
      int dy = yn_ - ym; dy = dy < 0 ? -dy : dy;
      int dx = xq_ - xm_; dx = dx < 0 ? -dx : dx;
      myd = sqv[(size_t)b * NPTS + m] - 2.0f * s + (ft[dy] + ft[dx]);
      myi = m;
    }
  }
  if (lane < NREF) {
    int rank = 0;
    for (int j = 0; j < NREF; ++j) {
      float dj = __shfl(myd, j); int ij = __shfl(myi, j);
      rank += (dj < myd || (dj == myd && ij < myi)) ? 1 : 0;
    }
    if (rank < 9) nn[(size_t)row * 9 + rank] = myi;
  }
}

// ---------------- K4: fused edge-gather + grouped GEMM via MFMA + GELU ----------------
__global__ __launch_bounds__(256, 4) void gc_kernel(
    const float* __restrict__ h, const int* __restrict__ nn,
    const unsigned short* __restrict__ wgh, const unsigned short* __restrict__ wgl,
    const float* __restrict__ bg, unsigned short* __restrict__ y)
{
  __shared__ __align__(16) char Wb[2 * 18432];   // [hi | lo], 96 rows x 192 B
  __shared__ int nns[576];
  const int tid = threadIdx.x;
  const int lane = tid & 63;
  const int w = tid >> 6;
  const int rt = blockIdx.x, g = blockIdx.y;
  const int n0g = rt * 64;
  const int b = n0g / NPTS;
  const size_t rowbase = (size_t)b * NPTS;
  const int cb = (g & 1) * CG;
  const int cn = lane & 15;
  const int kq = lane >> 4;
  const bool isD = (g >= 2);

  {
    const char* gh = (const char*)wgh + (size_t)g * 96 * 192;
    const char* gl = (const char*)wgl + (size_t)g * 96 * 192;
    for (int c = tid; c < 1152; c += 256) {
      int L = c * 16;
      int row = L / 192;
      int slot = (L % 192) >> 4;
      int sb = row * 192 + ((slot ^ (row & 3)) << 4);
      gl_lds16(gh + sb, Wb + L);
      gl_lds16(gl + sb, Wb + 18432 + L);
    }
  }
  if (isD) {
    for (int e = tid; e < 576; e += 256)
      nns[e] = nn[(size_t)(n0g + e / 9) * 9 + (e % 9)];
  }
  __syncthreads();   // DMA drained + nns visible

  const int rloc = w * 16 + cn;
  const int nb = n0g + rloc;
  bf16x8 gh8[3], gl8[3];
#pragma unroll
  for (int c = 0; c < 3; ++c) {
    const float* base = h + (size_t)nb * CH + cb + c * 32 + kq * 8;
    float4 x0 = *(const float4*)base;
    float4 x1 = *(const float4*)(base + 4);
    if (isD) {
      float4 m0 = make_float4(-INFINITY, -INFINITY, -INFINITY, -INFINITY);
      float4 m1 = m0;
#pragma unroll
      for (int k = 0; k < 9; ++k) {
        const float* nbase = h + (rowbase + nns[rloc * 9 + k]) * CH + cb + c * 32 + kq * 8;
        float4 n0v = *(const float4*)nbase;
        float4 n1v = *(const float4*)(nbase + 4);
        m0.x = fmaxf(m0.x, n0v.x); m0.y = fmaxf(m0.y, n0v.y);
        m0.z = fmaxf(m0.z, n0v.z); m0.w = fmaxf(m0.w, n0v.w);
        m1.x = fmaxf(m1.x, n1v.x); m1.y = fmaxf(m1.y, n1v.y);
        m1.z = fmaxf(m1.z, n1v.z); m1.w = fmaxf(m1.w, n1v.w);
      }
      x0.x = m0.x - x0.x; x0.y = m0.y - x0.y; x0.z = m0.z - x0.z; x0.w = m0.w - x0.w;
      x1.x = m1.x - x1.x; x1.y = m1.y - x1.y; x1.z = m1.z - x1.z; x1.w = m1.w - x1.w;
    }
    float v[8];
    *(float4*)&v[0] = x0;
    *(float4*)&v[4] = x1;
#pragma unroll
    for (int j = 0; j < 8; ++j) {
      unsigned short hh = f2bf(v[j]);
      gh8[c][j] = (short)hh;
      gl8[c][j] = (short)f2bf(v[j] - bf2f(hh));
    }
  }

#pragma unroll
  for (int sub = 0; sub < 6; ++sub) {
    f32x4 acc = {};
#pragma unroll
    for (int c = 0; c < 3; ++c) {
      int row = sub * 16 + cn;
      int slot = c * 4 + kq;
      int off = row * 192 + ((slot ^ (row & 3)) << 4);
      bf16x8 ah = *(const bf16x8*)(Wb + off);
      bf16x8 al = *(const bf16x8*)(Wb + 18432 + off);
      acc = __builtin_amdgcn_mfma_f32_16x16x32_bf16(ah, gh8[c], acc, 0, 0, 0);
      acc = __builtin_amdgcn_mfma_f32_16x16x32_bf16(ah, gl8[c], acc, 0, 0, 0);
      acc = __builtin_amdgcn_mfma_f32_16x16x32_bf16(al, gh8[c], acc, 0, 0, 0);
    }
    const int ocb = g * CG + sub * 16 + kq * 4;
    unsigned short pk[4];
#pragma unroll
    for (int i = 0; i < 4; ++i)
      pk[i] = f2bf(gelu_exact(acc[i] + bg[ocb + i]));
    *(ushort4*)&y[(size_t)nb * C2 + ocb] = *(ushort4*)pk;
  }
}

// ---------------- K5: fc2 via MFMA (y exact bf16; w2 hi/lo split) + BN2 + residual ----------------
__global__ __launch_bounds__(256, 4) void fc2_kernel(
    const unsigned short* __restrict__ yv,
    const unsigned short* __restrict__ w2h, const unsigned short* __restrict__ w2l,
    const float* __restrict__ b2, const float* __restrict__ x, float* __restrict__ out)
{
  __shared__ __align__(16) char Wb[2 * 12288];   // [hi 12288 | lo 12288] for 16-d subtile
  const int tid = threadIdx.x;
  const int lane = tid & 63;
  const int w = tid >> 6;
  const int rt = blockIdx.x, dg = blockIdx.y;
  const int n0g = rt * 64;
  const int b = n0g / NPTS;
  const int nloc0 = n0g - b * NPTS;
  const int cn = lane & 15;
  const int kk0 = (lane >> 4) * 8;

  bf16x8 yb[12];
  {
    const unsigned short* yp = yv + (size_t)(n0g + w * 16 + cn) * C2 + kk0;
#pragma unroll
    for (int c = 0; c < 12; ++c) yb[c] = *(const bf16x8*)(yp + c * 32);
  }

  int srcb[3], dstb[3];
#pragma unroll
  for (int j = 0; j < 3; ++j) {
    int L = (w * 3 + j) * 1024 + lane * 16;
    int r = L / 768, off = L % 768;
    srcb[j] = r * 768 + (off ^ ((r & 7) << 4));
    dstb[j] = (w * 3 + j) * 1024;
  }

  const char* gh = (const char*)w2h + (size_t)dg * 64 * 768;
  const char* gl = (const char*)w2l + (size_t)dg * 64 * 768;
  const int rr = cn;
  const int swz = (rr & 7) << 4;
  const int nsp = nloc0 + w * 16 + cn;

  for (int ds = 0; ds < 4; ++ds) {
    __syncthreads();
#pragma unroll
    for (int j = 0; j < 3; ++j) {
      gl_lds16(gh + ds * 12288 + srcb[j], Wb + dstb[j]);
      gl_lds16(gl + ds * 12288 + srcb[j], Wb + 12288 + dstb[j]);
    }
    __syncthreads();

    f32x4 acc_h = {}, acc_l = {};
#pragma unroll
    for (int c = 0; c < 12; ++c) {
      int off = rr * 768 + ((c * 64 + (lane >> 4) * 16) ^ swz);
      bf16x8 ah = *(const bf16x8*)(Wb + off);
      bf16x8 al = *(const bf16x8*)(Wb + 12288 + off);
      acc_h = __builtin_amdgcn_mfma_f32_16x16x32_bf16(ah, yb[c], acc_h, 0, 0, 0);
      acc_l = __builtin_amdgcn_mfma_f32_16x16x32_bf16(al, yb[c], acc_l, 0, 0, 0);
    }
    const int d0 = dg * 64 + ds * 16;
#pragma unroll
    for (int i = 0; i < 4; ++i) {
      int d = d0 + (lane >> 4) * 4 + i;
      size_t gi = ((size_t)b * CH + d) * NPTS + nsp;
      out[gi] = acc_h[i] + acc_l[i] + b2[d] + x[gi];
    }
  }
}

extern "C" void kernel_launch(void* const* d_in, const int* in_sizes, int n_in,
                              void* d_out, int out_size, void* d_ws, size_t ws_size,
                              hipStream_t stream) {
  const float* x     = (const float*)d_in[0];
  const float* fc1_w = (const float*)d_in[1];
  const float* fc1_b = (const float*)d_in[2];
  const float* bn1_g = (const float*)d_in[3];
  const float* bn1_b = (const float*)d_in[4];
  const float* bn1_m = (const float*)d_in[5];
  const float* bn1_v = (const float*)d_in[6];
  const float* gc_w  = (const float*)d_in[7];
  const float* gc_b  = (const float*)d_in[8];
  const float* bng_g = (const float*)d_in[9];
  const float* bng_b = (const float*)d_in[10];
  const float* bng_m = (const float*)d_in[11];
  const float* bng_v = (const float*)d_in[12];
  const float* fc2_w = (const float*)d_in[13];
  const float* fc2_b = (const float*)d_in[14];
  const float* bn2_g = (const float*)d_in[15];
  const float* bn2_b = (const float*)d_in[16];
  const float* bn2_m = (const float*)d_in[17];
  const float* bn2_v = (const float*)d_in[18];

  float* ws = (float*)d_ws;
  size_t o = 0;
  float* W1 = ws + o; o += 36864;
  float* B1 = ws + o; o += 192;
  unsigned short* WGH = (unsigned short*)(ws + o); o += 18432;
  unsigned short* WGL = (unsigned short*)(ws + o); o += 18432;
  float* BG = ws + o; o += 384;
  unsigned short* W2H = (unsigned short*)(ws + o); o += 36864;
  unsigned short* W2L = (unsigned short*)(ws + o); o += 36864;
  float* B2 = ws + o; o += 192;
  float* FT = ws + o; o += 64;
  float* H  = ws + o; o += (size_t)25088 * 192;     // 4,816,896 f32
  float* SQ = ws + o; o += 25088;
  int*   NN = (int*)(ws + o); o += 25088 * 9;
  float* SCR = ws + o;
  float* XT  = SCR;                                              // 4,816,896 f32 (dead after fc1)
  unsigned short* XHI = (unsigned short*)SCR;                    // overlays XT after fc1
  unsigned short* XLO = XHI + (size_t)4816896;                   // 4,816,896 u16
  float* XN  = SCR + (size_t)4816896;                            // 4,816,896 f32
  unsigned short* YB = (unsigned short*)XN;                      // overlays XN
  unsigned* PD = (unsigned*)(XN + (size_t)4816896);              // 25088*48 u32
  (void)ws_size; (void)in_sizes; (void)n_in; (void)out_size;

  hipLaunchKernelGGL(prep_kernel, dim3(580), dim3(256), 0, stream,
                     fc1_w, fc1_b, bn1_g, bn1_b, bn1_m, bn1_v,
                     gc_w, gc_b, bng_g, bng_b, bng_m, bng_v,
                     fc2_w, fc2_b, bn2_g, bn2_b, bn2_m, bn2_v,
                     W1, B1, WGH, WGL, BG, W2H, W2L, B2, FT);
  hipLaunchKernelGGL(xt_kernel, dim3(49, 3, 8), dim3(256), 0, stream, x, XT);
  hipLaunchKernelGGL(fc1_kernel, dim3(49, 3, 8), dim3(256), 0, stream, XT, W1, B1, H);
  hipLaunchKernelGGL(norm_kernel, dim3(6272), dim3(256), 0, stream, H, XN, XHI, XLO, SQ);
  hipLaunchKernelGGL(topk_kernel, dim3(NT128 * MSPLIT * 8), dim3(256), 0, stream, XHI, XLO, FT, PD);
  hipLaunchKernelGGL(refine_kernel, dim3(6272), dim3(256), 0, stream, PD, XN, SQ, FT, NN);
  hipLaunchKernelGGL(gc_kernel, dim3(392, 4), dim3(256), 0, stream, H, NN, WGH, WGL, BG, YB);
  hipLaunchKernelGGL(fc2_kernel, dim3(392, 3), dim3(256), 0, stream, YB, W2H, W2L, B2, x, (float*)d_out);
}

// Round 19
// 360.784 us; speedup vs baseline: 1.0388x; 1.0388x over previous
//
#include <hip/hip_runtime.h>
#include <math.h>

#define BATCH 8
#define CH    192
#define WW    56
#define NPTS  3136
#define C2    384
#define CG    96
#define MT    32
#define MSPLIT 4
#define LK    12
#define NCAND (MSPLIT*LK)
#define NREF  16
#define MQ    (NPTS/MSPLIT)   // 784 rows per m-quarter; 784 = 24*32 + 16

typedef float f32x4 __attribute__((ext_vector_type(4)));
typedef short bf16x8 __attribute__((ext_vector_type(8)));

__device__ __forceinline__ float gelu_exact(float v) {
  return 0.5f * v * (1.0f + erff(v * 0.7071067811865475f));
}
__device__ __forceinline__ unsigned short f2bf(float f) {
  unsigned int u = __float_as_uint(f);
  u = u + 0x7fffu + ((u >> 16) & 1u);
  return (unsigned short)(u >> 16);
}
__device__ __forceinline__ float bf2f(unsigned short h) {
  return __uint_as_float(((unsigned int)h) << 16);
}
__device__ __forceinline__ void gl_lds16(const void* g, void* lds) {
  __builtin_amdgcn_global_load_lds(
      (const __attribute__((address_space(1))) unsigned int*)g,
      (__attribute__((address_space(3))) unsigned int*)lds, 16, 0, 0);
}
// order-preserving f32 -> u32 (ascending)
__device__ __forceinline__ unsigned fmono(float f) {
  unsigned u = __float_as_uint(f);
  return u ^ ((unsigned)((int)u >> 31) | 0x80000000u);
}
__device__ __forceinline__ unsigned umin32(unsigned a, unsigned b) { return a < b ? a : b; }
__device__ __forceinline__ unsigned umax32(unsigned a, unsigned b) { return a < b ? b : a; }

// ---------------- K0: fold BN into weights; wg & w2 -> bf16 hi/lo; cos-table ----------------
// fc1 weights stay f32: h feeds neighbor selection; only the bitwise-stable
// f32 recipe is flip-safe (round-10 lesson).
__global__ void prep_kernel(
    const float* __restrict__ fc1_w, const float* __restrict__ fc1_b,
    const float* __restrict__ bn1_g, const float* __restrict__ bn1_b,
    const float* __restrict__ bn1_m, const float* __restrict__ bn1_v,
    const float* __restrict__ gc_w,  const float* __restrict__ gc_b,
    const float* __restrict__ bng_g, const float* __restrict__ bng_b,
    const float* __restrict__ bng_m, const float* __restrict__ bng_v,
    const float* __restrict__ fc2_w, const float* __restrict__ fc2_b,
    const float* __restrict__ bn2_g, const float* __restrict__ bn2_b,
    const float* __restrict__ bn2_m, const float* __restrict__ bn2_v,
    float* __restrict__ w1, float* __restrict__ b1,
    unsigned short* __restrict__ wgh, unsigned short* __restrict__ wgl,
    float* __restrict__ bg,
    unsigned short* __restrict__ w2h, unsigned short* __restrict__ w2l,
    float* __restrict__ b2, float* __restrict__ ftab)
{
  int i = blockIdx.x * 256 + threadIdx.x;
  if (i < 36864) {
    int d = i / CH;
    float s = bn1_g[d] / sqrtf(bn1_v[d] + 1e-5f);
    w1[i] = fc1_w[i] * s;
  } else if (i < 37056) {
    int d = i - 36864;
    float s = bn1_g[d] / sqrtf(bn1_v[d] + 1e-5f);
    b1[d] = (fc1_b[d] - bn1_m[d]) * s + bn1_b[d];
  } else if (i < 73920) {
    int j = i - 37056;
    int o = j / CG;
    float s = bng_g[o] / sqrtf(bng_v[o] + 1e-5f);
    float v = gc_w[j] * s;
    unsigned short hi = f2bf(v);
    wgh[j] = hi;
    wgl[j] = f2bf(v - bf2f(hi));
  } else if (i < 74304) {
    int o = i - 73920;
    float s = bng_g[o] / sqrtf(bng_v[o] + 1e-5f);
    bg[o] = (gc_b[o] - bng_m[o]) * s + bng_b[o];
  } else if (i < 148032) {
    int j = i - 74304;
    int d = j / C2;
    float s = bn2_g[d] / sqrtf(bn2_v[d] + 1e-5f);
    float v = fc2_w[j] * s;
    unsigned short hi = f2bf(v);
    w2h[j] = hi;
    w2l[j] = f2bf(v - bf2f(hi));
  } else if (i < 148224) {
    int d = i - 148032;
    float s = bn2_g[d] / sqrtf(bn2_v[d] + 1e-5f);
    b2[d] = (fc2_b[d] - bn2_m[d]) * s + bn2_b[d];
  } else if (i < 148280) {
    int delta = i - 148224;
    float s = 0.f;
    for (int t = 0; t < 48; ++t) {
      float omega = powf(10000.f, -(float)t / 48.f);
      s += cosf((float)delta * omega);
    }
    ftab[delta] = s * (-2.0f / (float)CH);   // pre-scaled: rel = ft[dy]+ft[dx]
  }
}

// ---------------- K0b: exact transpose x -> xt[b][n][k] (bitwise copy) ----------------
__global__ __launch_bounds__(256) void xt_kernel(
    const float* __restrict__ x, float* __restrict__ xt)
{
  __shared__ float T[64 * 65];
  const int tid = threadIdx.x;
  const int nt = blockIdx.x, kt = blockIdx.y, b = blockIdx.z;
  const int n0 = nt * 64, k0 = kt * 64;
  const float* xb = x + (size_t)b * CH * NPTS;
#pragma unroll
  for (int p = 0; p < 16; ++p) {
    int e = p * 256 + tid;
    int kk = e >> 6, r = e & 63;
    T[kk * 65 + r] = xb[(size_t)(k0 + kk) * NPTS + n0 + r];
  }
  __syncthreads();
#pragma unroll
  for (int p = 0; p < 4; ++p) {
    int e = p * 256 + tid;
    int r = e >> 4, k4 = (e & 15) << 2;
    float4 v;
    v.x = T[(k4 + 0) * 65 + r];
    v.y = T[(k4 + 1) * 65 + r];
    v.z = T[(k4 + 2) * 65 + r];
    v.w = T[(k4 + 3) * 65 + r];
    *(float4*)&xt[((size_t)b * NPTS + n0 + r) * CH + k0 + k4] = v;
  }
}

// ---------------- K1: h = BN1(fc1) ; f32 64x64 tile, swizzled LDS (r17 form) ----------------
__global__ __launch_bounds__(256) void fc1_kernel(
    const float* __restrict__ xt, const float* __restrict__ w1,
    const float* __restrict__ b1, float* __restrict__ h)
{
  __shared__ float As[64*68];
  __shared__ float Bs[64*68];
  const int tid = threadIdx.x;
  const int ntile = blockIdx.x, dt = blockIdx.y, b = blockIdx.z;
  const int n0 = ntile * 64, d0 = dt * 64;
  const int ty = tid >> 4, tx = tid & 15;
  const float* xa = xt + ((size_t)b * NPTS + n0) * CH;
  const float* wb = w1 + (size_t)d0 * CH;
  const int tya = ty & 7, txa = tx & 7;
  float acc[4][4] = {};
  for (int k0 = 0; k0 < CH; k0 += 64) {
    if (k0) __syncthreads();
#pragma unroll
    for (int p = 0; p < 4; ++p) {
      int e = p * 256 + tid;
      int r = e >> 4, c4 = e & 15;
      int col = (c4 ^ ((r >> 2) & 7)) << 2;
      *(float4*)&As[r*68 + col] = *(const float4*)&xa[(size_t)r * CH + k0 + (c4 << 2)];
      *(float4*)&Bs[r*68 + col] = *(const float4*)&wb[(size_t)r * CH + k0 + (c4 << 2)];
    }
    __syncthreads();
#pragma unroll
    for (int kq = 0; kq < 16; ++kq) {
      const int ca = (kq ^ tya) << 2;
      const int cb = (kq ^ txa) << 2;
      float4 av[4], bv[4];
#pragma unroll
      for (int i = 0; i < 4; ++i) av[i] = *(const float4*)&As[(ty*4+i)*68 + ca];
#pragma unroll
      for (int j = 0; j < 4; ++j) bv[j] = *(const float4*)&Bs[(tx*4+j)*68 + cb];
#pragma unroll
      for (int i = 0; i < 4; ++i)
#pragma unroll
        for (int j = 0; j < 4; ++j)
          acc[i][j] += av[i].x*bv[j].x + av[i].y*bv[j].y + av[i].z*bv[j].z + av[i].w*bv[j].w;
    }
  }
#pragma unroll
  for (int i = 0; i < 4; ++i) {
    int n = n0 + ty*4 + i;
    float4 v;
    v.x = acc[i][0] + b1[d0 + tx*4 + 0];
    v.y = acc[i][1] + b1[d0 + tx*4 + 1];
    v.z = acc[i][2] + b1[d0 + tx*4 + 2];
    v.w = acc[i][3] + b1[d0 + tx*4 + 3];
    *(float4*)&h[((size_t)b * NPTS + n) * CH + d0 + tx*4] = v;
  }
}

// ---------------- K2: xn (f32 + bf16 hi/lo split) + sq ----------------
__global__ __launch_bounds__(256) void norm_kernel(
    const float* __restrict__ h, float* __restrict__ xnf,
    unsigned short* __restrict__ xhi, unsigned short* __restrict__ xlo,
    float* __restrict__ sqv)
{
  const int lane = threadIdx.x & 63;
  const int row = blockIdx.x * 4 + (threadIdx.x >> 6);
  const float* hr = h + (size_t)row * CH;
  float v0 = hr[lane], v1 = hr[lane + 64], v2 = hr[lane + 128];
  float s = v0*v0 + v1*v1 + v2*v2;
#pragma unroll
  for (int o = 32; o > 0; o >>= 1) s += __shfl_xor(s, o);
  float inv = 1.0f / fmaxf(sqrtf(s), 1e-12f);
  float x0 = v0 * inv, x1 = v1 * inv, x2 = v2 * inv;
  size_t base = (size_t)row * CH;
  xnf[base + lane      ] = x0;
  xnf[base + lane + 64 ] = x1;
  xnf[base + lane + 128] = x2;
  unsigned short h0 = f2bf(x0), h1 = f2bf(x1), h2 = f2bf(x2);
  xhi[base + lane      ] = h0;
  xhi[base + lane + 64 ] = h1;
  xhi[base + lane + 128] = h2;
  xlo[base + lane      ] = f2bf(x0 - bf2f(h0));
  xlo[base + lane + 64 ] = f2bf(x1 - bf2f(h1));
  xlo[base + lane + 128] = f2bf(x2 - bf2f(h2));
  if (lane == 0) sqv[row] = s * inv * inv;
}

// ---------------- K3: MFMA coarse dist, per-lane packed-key top-12 ----------------
__global__ __launch_bounds__(256, 3) void topk_kernel(
    const unsigned short* __restrict__ xhi, const unsigned short* __restrict__ xlo,
    const float* __restrict__ fts_g,
    unsigned* __restrict__ pd)
{
  __shared__ __align__(16) char LDSbuf[2 * 24576];   // [buf][hi 12288 | lo 12288]
  __shared__ float ft[64];

  const int tid  = threadIdx.x;
  const int lane = tid & 63;
  const int w    = tid >> 6;
  const int bid  = blockIdx.x;
  const int b    = bid & 7;            // XCD-aligned (round-robin assumption)
  const int r_   = bid >> 3;
  const int ms   = r_ / 49;
  const int nt   = r_ % 49;
  const int n0 = nt * 64;
  const size_t rowbase = (size_t)b * NPTS;

  if (tid < 64) ft[tid] = (tid < 56) ? fts_g[tid] : 0.0f;

  const int ar = lane & 15;
  const int hi = lane >> 4;
  const int ak = hi * 8;

  const int n_b = n0 + w * 16 + ar;
  bf16x8 bhi[6], blo[6];
  {
    const unsigned short* pbh = xhi + (rowbase + n_b) * CH + ak;
    const unsigned short* pbl = xlo + (rowbase + n_b) * CH + ak;
#pragma unroll
    for (int c = 0; c < 6; ++c) {
      bhi[c] = *(const bf16x8*)(pbh + c * 32);
      blo[c] = *(const bf16x8*)(pbl + c * 32);
    }
  }
  const int yn_l = n_b / WW, xn_l = n_b % WW;

  unsigned ld[LK];
#pragma unroll
  for (int k = 0; k < LK; ++k) ld[k] = 0xFFFFFFFFu;

  int srcb[6];
#pragma unroll
  for (int j = 0; j < 6; ++j) {
    int L = (w & 1) * 6144 + j * 1024 + lane * 16;
    int r = L / 384, off = L % 384;
    srcb[j] = r * 384 + (off ^ ((r & 7) << 4));
  }
  const int ldsb = (w >= 2 ? 12288 : 0) + (w & 1) * 6144;

  const int mbase = ms * MQ;
  const char* gb = (w < 2 ? (const char*)xhi : (const char*)xlo)
                   + (rowbase + mbase) * (CH * 2);

#define STAGE(BUF) do {                                                     \
  _Pragma("unroll")                                                         \
  for (int j = 0; j < 6; ++j)                                               \
    gl_lds16(gb + srcb[j], LDSbuf + (BUF) * 24576 + ldsb + j * 1024);       \
} while (0)

  STAGE(0);
  gb += 12288;

  int ym0 = ms * 14, xm0 = 0;

  for (int tt = 0; tt < 25; ++tt) {
    __syncthreads();
    if (tt + 1 < 25) { STAGE((tt + 1) & 1); gb += 12288; }

    const int bufb = (tt & 1) * 24576;
    const int swz = (ar & 7) << 4;
    const float fdy0 = ft[abs(yn_l - ym0)];
    const float fdy1 = ft[abs(yn_l - ym0 - 1)];
    const int nrt = (tt == 24) ? 1 : 2;
#pragma unroll
    for (int rt = 0; rt < 2; ++rt) {
      if (rt >= nrt) break;
      const int rA = rt * 16 + ar;
      f32x4 a_hh = {}, a_hl = {}, a_lh = {};
#pragma unroll
      for (int c = 0; c < 6; ++c) {
        int off = bufb + rA * 384 + ((c * 64 + hi * 16) ^ swz);
        bf16x8 ah = *(const bf16x8*)(LDSbuf + off);
        bf16x8 al = *(const bf16x8*)(LDSbuf + off + 12288);
        a_hh = __builtin_amdgcn_mfma_f32_16x16x32_bf16(ah, bhi[c], a_hh, 0, 0, 0);
        a_hl = __builtin_amdgcn_mfma_f32_16x16x32_bf16(ah, blo[c], a_hl, 0, 0, 0);
        a_lh = __builtin_amdgcn_mfma_f32_16x16x32_bf16(al, bhi[c], a_lh, 0, 0, 0);
      }
      f32x4 s4;
#pragma unroll
      for (int i = 0; i < 4; ++i) s4[i] = a_hh[i] + (a_hl[i] + a_lh[i]);

      const int locb = tt * MT + rt * 16 + hi * 4;
      unsigned kk[4];
#pragma unroll
      for (int i = 0; i < 4; ++i) {
        int xm = xm0 + rt * 16 + hi * 4 + i;
        const bool wrap = (xm >= WW);
        if (wrap) xm -= WW;
        int dx = xn_l - xm; dx = dx < 0 ? -dx : dx;
        float d_ = (wrap ? fdy1 : fdy0) + ft[dx] - 2.0f * s4[i];
        kk[i] = (fmono(d_) & 0xFFFFFC00u) | (unsigned)(locb + i);
      }
      {
        unsigned sa = umax32(kk[0], kk[1]), sb = umin32(kk[0], kk[1]);
        unsigned sc = umax32(kk[2], kk[3]), sd = umin32(kk[2], kk[3]);
        unsigned v0 = umax32(sa, sc), t1 = umin32(sa, sc);
        unsigned t2 = umax32(sb, sd), v3 = umin32(sb, sd);
        unsigned v1 = umax32(t1, t2), v2 = umin32(t1, t2);
        unsigned l4 = umin32(ld[4], v0), g4 = umax32(ld[4], v0);
        unsigned l5 = umin32(ld[5], v1), g5 = umax32(ld[5], v1);
        unsigned l6 = umin32(ld[6], v2), g6 = umax32(ld[6], v2);
        unsigned l7 = umin32(ld[7], v3), g7 = umax32(ld[7], v3);
        unsigned a0 = umin32(ld[0], l4), b0 = umax32(ld[0], l4);
        unsigned a1 = umin32(ld[1], l5), b1 = umax32(ld[1], l5);
        unsigned a2 = umin32(ld[2], l6), b2 = umax32(ld[2], l6);
        unsigned a3 = umin32(ld[3], l7), b3 = umax32(ld[3], l7);
        unsigned q0 = umin32(a0, a2), q2 = umax32(a0, a2);
        unsigned q1 = umin32(a1, a3), q3 = umax32(a1, a3);
        unsigned r0 = umin32(b0, b2), r2 = umax32(b0, b2);
        unsigned r1 = umin32(b1, b3), r3 = umax32(b1, b3);
        ld[0] = umin32(q0, q1); ld[1] = umax32(q0, q1);
        ld[2] = umin32(q2, q3); ld[3] = umax32(q2, q3);
        ld[4] = umin32(r0, r1); ld[5] = umax32(r0, r1);
        ld[6] = umin32(r2, r3); ld[7] = umax32(r2, r3);
        unsigned e0 = umin32(ld[8],  g4);
        unsigned e1 = umin32(ld[9],  g5);
        unsigned e2 = umin32(ld[10], g6);
        unsigned e3 = umin32(ld[11], g7);
        unsigned f0 = umin32(e0, e2), f2 = umax32(e0, e2);
        unsigned f1 = umin32(e1, e3), f3 = umax32(e1, e3);
        ld[8]  = umin32(f0, f1); ld[9]  = umax32(f0, f1);
        ld[10] = umin32(f2, f3); ld[11] = umax32(f2, f3);
      }
    }
    xm0 += MT;
    if (xm0 >= WW) { xm0 -= WW; ym0 += 1; }
  }

  __syncthreads();
  unsigned* Md = (unsigned*)LDSbuf;
#pragma unroll
  for (int k = 0; k < LK; ++k) Md[tid * LK + k] = ld[k];
  __syncthreads();
  if (tid < 64) {
    const int wv = tid >> 4, arr = tid & 15;
    const int n = n0 + tid;
    int lb[4];
#pragma unroll
    for (int hq = 0; hq < 4; ++hq) lb[hq] = (wv * 64 + hq * 16 + arr) * LK;
    int p0 = 0, p1 = 0, p2 = 0, p3 = 0;
    unsigned* od = pd + ((rowbase + n) * MSPLIT + ms) * LK;
    for (int k = 0; k < LK; ++k) {
      unsigned bk = Md[lb[0] + p0]; int bq = 0;
      unsigned v1 = Md[lb[1] + p1];
      if (v1 < bk) { bk = v1; bq = 1; }
      unsigned v2 = Md[lb[2] + p2];
      if (v2 < bk) { bk = v2; bq = 2; }
      unsigned v3 = Md[lb[3] + p3];
      if (v3 < bk) { bk = v3; bq = 3; }
      if (bq == 0) { if (p0 < LK-1) ++p0; else Md[lb[0]+p0] = 0xFFFFFFFFu; }
      else if (bq == 1) { if (p1 < LK-1) ++p1; else Md[lb[1]+p1] = 0xFFFFFFFFu; }
      else if (bq == 2) { if (p2 < LK-1) ++p2; else Md[lb[2]+p2] = 0xFFFFFFFFu; }
      else              { if (p3 < LK-1) ++p3; else Md[lb[3]+p3] = 0xFFFFFFFFu; }
      od[k] = bk;
    }
  }
#undef STAGE
}

// ---------------- K3b: pool 48 packed coarse keys -> exact f32 refine -> top-9 ----------------
__global__ __launch_bounds__(256) void refine_kernel(
    const unsigned* __restrict__ pd,
    const float* __restrict__ xn, const float* __restrict__ sqv,
    const float* __restrict__ fts_g, int* __restrict__ nn)
{
  __shared__ unsigned allk[4][NCAND];
  __shared__ int      ci_s[4][NREF];
  __shared__ float ft[56];
  const int tid = threadIdx.x;
  const int w = tid >> 6, lane = tid & 63;
  if (tid < 56) ft[tid] = fts_g[tid];
  const int row = blockIdx.x * 4 + w;
  const int b = row / NPTS;
  const int n_loc = row - b * NPTS;

  if (lane < NCAND) allk[w][lane] = pd[(size_t)row * NCAND + lane];
  __syncthreads();
  if (lane < NCAND) {
    unsigned k0 = allk[w][lane];
    int rank = 0;
    for (int j = 0; j < NCAND; ++j) {
      unsigned kj = allk[w][j];
      rank += (kj < k0 || (kj == k0 && j < lane)) ? 1 : 0;
    }
    if (rank < NREF) ci_s[w][rank] = (lane / LK) * MQ + (int)(k0 & 1023u);
  }
  __syncthreads();

  const float* xrow = xn + (size_t)row * CH;
  float a0 = xrow[lane], a1 = xrow[lane + 64], a2 = xrow[lane + 128];
  const int yn_ = n_loc / WW, xq_ = n_loc % WW;
  const size_t xbase = (size_t)b * NPTS * CH;

  int cm[NREF];
  float xv0[NREF], xv1[NREF], xv2[NREF];
#pragma unroll
  for (int c = 0; c < NREF; ++c) {
    int m = ci_s[w][c];
    cm[c] = m;
    const float* xm = xn + xbase + (size_t)m * CH;
    xv0[c] = xm[lane];
    xv1[c] = xm[lane + 64];
    xv2[c] = xm[lane + 128];
  }

  float myd = INFINITY; int myi = 0x7fffffff;
#pragma unroll
  for (int c = 0; c < NREF; ++c) {
    float s = a0 * xv0[c] + a1 * xv1[c] + a2 * xv2[c];
#pragma unroll
    for (int o = 32; o > 0; o >>= 1) s += __shfl_xor(s, o);
    if (lane == c) {
      int m = cm[c];
      int ym = m / WW, xm_ = m % WW;
      int dy = yn_ - ym; dy = dy < 0 ? -dy : dy;
      int dx = xq_ - xm_; dx = dx < 0 ? -dx : dx;
      myd = sqv[(size_t)b * NPTS + m] - 2.0f * s + (ft[dy] + ft[dx]);
      myi = m;
    }
  }
  if (lane < NREF) {
    int rank = 0;
    for (int j = 0; j < NREF; ++j) {
      float dj = __shfl(myd, j); int ij = __shfl(myi, j);
      rank += (dj < myd || (dj == myd && ij < myi)) ? 1 : 0;
    }
    if (rank < 9) nn[(size_t)row * 9 + rank] = myi;
  }
}

// ---------------- K4: fused edge-gather + grouped GEMM via MFMA + GELU ----------------
__global__ __launch_bounds__(256, 4) void gc_kernel(
    const float* __restrict__ h, const int* __restrict__ nn,
    const unsigned short* __restrict__ wgh, const unsigned short* __restrict__ wgl,
    const float* __restrict__ bg, unsigned short* __restrict__ y)
{
  __shared__ __align__(16) char Wb[2 * 18432];   // [hi | lo], 96 rows x 192 B
  __shared__ int nns[576];
  const int tid = threadIdx.x;
  const int lane = tid & 63;
  const int w = tid >> 6;
  const int rt = blockIdx.x, g = blockIdx.y;
  const int n0g = rt * 64;
  const int b = n0g / NPTS;
  const size_t rowbase = (size_t)b * NPTS;
  const int cb = (g & 1) * CG;
  const int cn = lane & 15;
  const int kq = lane >> 4;
  const bool isD = (g >= 2);

  {
    const char* gh = (const char*)wgh + (size_t)g * 96 * 192;
    const char* gl = (const char*)wgl + (size_t)g * 96 * 192;
    for (int c = tid; c < 1152; c += 256) {
      int L = c * 16;
      int row = L / 192;
      int slot = (L % 192) >> 4;
      int sb = row * 192 + ((slot ^ (row & 3)) << 4);
      gl_lds16(gh + sb, Wb + L);
      gl_lds16(gl + sb, Wb + 18432 + L);
    }
  }
  if (isD) {
    for (int e = tid; e < 576; e += 256)
      nns[e] = nn[(size_t)(n0g + e / 9) * 9 + (e % 9)];
  }
  __syncthreads();   // DMA drained + nns visible

  const int rloc = w * 16 + cn;
  const int nb = n0g + rloc;
  bf16x8 gh8[3], gl8[3];
#pragma unroll
  for (int c = 0; c < 3; ++c) {
    const float* base = h + (size_t)nb * CH + cb + c * 32 + kq * 8;
    float4 x0 = *(const float4*)base;
    float4 x1 = *(const float4*)(base + 4);
    if (isD) {
      float4 m0 = make_float4(-INFINITY, -INFINITY, -INFINITY, -INFINITY);
      float4 m1 = m0;
#pragma unroll
      for (int k = 0; k < 9; ++k) {
        const float* nbase = h + (rowbase + nns[rloc * 9 + k]) * CH + cb + c * 32 + kq * 8;
        float4 n0v = *(const float4*)nbase;
        float4 n1v = *(const float4*)(nbase + 4);
        m0.x = fmaxf(m0.x, n0v.x); m0.y = fmaxf(m0.y, n0v.y);
        m0.z = fmaxf(m0.z, n0v.z); m0.w = fmaxf(m0.w, n0v.w);
        m1.x = fmaxf(m1.x, n1v.x); m1.y = fmaxf(m1.y, n1v.y);
        m1.z = fmaxf(m1.z, n1v.z); m1.w = fmaxf(m1.w, n1v.w);
      }
      x0.x = m0.x - x0.x; x0.y = m0.y - x0.y; x0.z = m0.z - x0.z; x0.w = m0.w - x0.w;
      x1.x = m1.x - x1.x; x1.y = m1.y - x1.y; x1.z = m1.z - x1.z; x1.w = m1.w - x1.w;
    }
    float v[8];
    *(float4*)&v[0] = x0;
    *(float4*)&v[4] = x1;
#pragma unroll
    for (int j = 0; j < 8; ++j) {
      unsigned short hh = f2bf(v[j]);
      gh8[c][j] = (short)hh;
      gl8[c][j] = (short)f2bf(v[j] - bf2f(hh));
    }
  }

#pragma unroll
  for (int sub = 0; sub < 6; ++sub) {
    f32x4 acc = {};
#pragma unroll
    for (int c = 0; c < 3; ++c) {
      int row = sub * 16 + cn;
      int slot = c * 4 + kq;
      int off = row * 192 + ((slot ^ (row & 3)) << 4);
      bf16x8 ah = *(const bf16x8*)(Wb + off);
      bf16x8 al = *(const bf16x8*)(Wb + 18432 + off);
      acc = __builtin_amdgcn_mfma_f32_16x16x32_bf16(ah, gh8[c], acc, 0, 0, 0);
      acc = __builtin_amdgcn_mfma_f32_16x16x32_bf16(ah, gl8[c], acc, 0, 0, 0);
      acc = __builtin_amdgcn_mfma_f32_16x16x32_bf16(al, gh8[c], acc, 0, 0, 0);
    }
    const int ocb = g * CG + sub * 16 + kq * 4;
    unsigned short pk[4];
#pragma unroll
    for (int i = 0; i < 4; ++i)
      pk[i] = f2bf(gelu_exact(acc[i] + bg[ocb + i]));
    *(ushort4*)&y[(size_t)nb * C2 + ocb] = *(ushort4*)pk;
  }
}

// ---------------- K5: fc2 via MFMA (y exact bf16; w2 hi/lo split) + BN2 + residual ----------------
__global__ __launch_bounds__(256, 4) void fc2_kernel(
    const unsigned short* __restrict__ yv,
    const unsigned short* __restrict__ w2h, const unsigned short* __restrict__ w2l,
    const float* __restrict__ b2, const float* __restrict__ x, float* __restrict__ out)
{
  __shared__ __align__(16) char Wb[2 * 12288];   // [hi 12288 | lo 12288] for 16-d subtile
  const int tid = threadIdx.x;
  const int lane = tid & 63;
  const int w = tid >> 6;
  const int rt = blockIdx.x, dg = blockIdx.y;
  const int n0g = rt * 64;
  const int b = n0g / NPTS;
  const int nloc0 = n0g - b * NPTS;
  const int cn = lane & 15;
  const int kk0 = (lane >> 4) * 8;

  bf16x8 yb[12];
  {
    const unsigned short* yp = yv + (size_t)(n0g + w * 16 + cn) * C2 + kk0;
#pragma unroll
    for (int c = 0; c < 12; ++c) yb[c] = *(const bf16x8*)(yp + c * 32);
  }

  int srcb[3], dstb[3];
#pragma unroll
  for (int j = 0; j < 3; ++j) {
    int L = (w * 3 + j) * 1024 + lane * 16;
    int r = L / 768, off = L % 768;
    srcb[j] = r * 768 + (off ^ ((r & 7) << 4));
    dstb[j] = (w * 3 + j) * 1024;
  }

  const char* gh = (const char*)w2h + (size_t)dg * 64 * 768;
  const char* gl = (const char*)w2l + (size_t)dg * 64 * 768;
  const int rr = cn;
  const int swz = (rr & 7) << 4;
  const int nsp = nloc0 + w * 16 + cn;

  for (int ds = 0; ds < 4; ++ds) {
    __syncthreads();
#pragma unroll
    for (int j = 0; j < 3; ++j) {
      gl_lds16(gh + ds * 12288 + srcb[j], Wb + dstb[j]);
      gl_lds16(gl + ds * 12288 + srcb[j], Wb + 12288 + dstb[j]);
    }
    __syncthreads();

    f32x4 acc_h = {}, acc_l = {};
#pragma unroll
    for (int c = 0; c < 12; ++c) {
      int off = rr * 768 + ((c * 64 + (lane >> 4) * 16) ^ swz);
      bf16x8 ah = *(const bf16x8*)(Wb + off);
      bf16x8 al = *(const bf16x8*)(Wb + 12288 + off);
      acc_h = __builtin_amdgcn_mfma_f32_16x16x32_bf16(ah, yb[c], acc_h, 0, 0, 0);
      acc_l = __builtin_amdgcn_mfma_f32_16x16x32_bf16(al, yb[c], acc_l, 0, 0, 0);
    }
    const int d0 = dg * 64 + ds * 16;
#pragma unroll
    for (int i = 0; i < 4; ++i) {
      int d = d0 + (lane >> 4) * 4 + i;
      size_t gi = ((size_t)b * CH + d) * NPTS + nsp;
      out[gi] = acc_h[i] + acc_l[i] + b2[d] + x[gi];
    }
  }
}

extern "C" void kernel_launch(void* const* d_in, const int* in_sizes, int n_in,
                              void* d_out, int out_size, void* d_ws, size_t ws_size,
                              hipStream_t stream) {
  const float* x     = (const float*)d_in[0];
  const float* fc1_w = (const float*)d_in[1];
  const float* fc1_b = (const float*)d_in[2];
  const float* bn1_g = (const float*)d_in[3];
  const float* bn1_b = (const float*)d_in[4];
  const float* bn1_m = (const float*)d_in[5];
  const float* bn1_v = (const float*)d_in[6];
  const float* gc_w  = (const float*)d_in[7];
  const float* gc_b  = (const float*)d_in[8];
  const float* bng_g = (const float*)d_in[9];
  const float* bng_b = (const float*)d_in[10];
  const float* bng_m = (const float*)d_in[11];
  const float* bng_v = (const float*)d_in[12];
  const float* fc2_w = (const float*)d_in[13];
  const float* fc2_b = (const float*)d_in[14];
  const float* bn2_g = (const float*)d_in[15];
  const float* bn2_b = (const float*)d_in[16];
  const float* bn2_m = (const float*)d_in[17];
  const float* bn2_v = (const float*)d_in[18];

  float* ws = (float*)d_ws;
  size_t o = 0;
  float* W1 = ws + o; o += 36864;
  float* B1 = ws + o; o += 192;
  unsigned short* WGH = (unsigned short*)(ws + o); o += 18432;
  unsigned short* WGL = (unsigned short*)(ws + o); o += 18432;
  float* BG = ws + o; o += 384;
  unsigned short* W2H = (unsigned short*)(ws + o); o += 36864;
  unsigned short* W2L = (unsigned short*)(ws + o); o += 36864;
  float* B2 = ws + o; o += 192;
  float* FT = ws + o; o += 64;
  float* H  = ws + o; o += (size_t)25088 * 192;     // 4,816,896 f32
  float* SQ = ws + o; o += 25088;
  int*   NN = (int*)(ws + o); o += 25088 * 9;
  float* SCR = ws + o;
  float* XT  = SCR;                                              // 4,816,896 f32 (dead after fc1)
  unsigned short* XHI = (unsigned short*)SCR;                    // overlays XT after fc1
  unsigned short* XLO = XHI + (size_t)4816896;                   // 4,816,896 u16
  float* XN  = SCR + (size_t)4816896;                            // 4,816,896 f32
  unsigned short* YB = (unsigned short*)XN;                      // overlays XN
  unsigned* PD = (unsigned*)(XN + (size_t)4816896);              // 25088*48 u32
  (void)ws_size; (void)in_sizes; (void)n_in; (void)out_size;

  hipLaunchKernelGGL(prep_kernel, dim3(580), dim3(256), 0, stream,
                     fc1_w, fc1_b, bn1_g, bn1_b, bn1_m, bn1_v,
                     gc_w, gc_b, bng_g, bng_b, bng_m, bng_v,
                     fc2_w, fc2_b, bn2_g, bn2_b, bn2_m, bn2_v,
                     W1, B1, WGH, WGL, BG, W2H, W2L, B2, FT);
  hipLaunchKernelGGL(xt_kernel, dim3(49, 3, 8), dim3(256), 0, stream, x, XT);
  hipLaunchKernelGGL(fc1_kernel, dim3(49, 3, 8), dim3(256), 0, stream, XT, W1, B1, H);
  hipLaunchKernelGGL(norm_kernel, dim3(6272), dim3(256), 0, stream, H, XN, XHI, XLO, SQ);
  hipLaunchKernelGGL(topk_kernel, dim3(49 * MSPLIT * 8), dim3(256), 0, stream, XHI, XLO, FT, PD);
  hipLaunchKernelGGL(refine_kernel, dim3(6272), dim3(256), 0, stream, PD, XN, SQ, FT, NN);
  hipLaunchKernelGGL(gc_kernel, dim3(392, 4), dim3(256), 0, stream, H, NN, WGH, WGL, BG, YB);
  hipLaunchKernelGGL(fc2_kernel, dim3(392, 3), dim3(256), 0, stream, YB, W2H, W2L, B2, x, (float*)d_out);
}